// Round 1
// baseline (2438.851 us; speedup 1.0000x reference)
//
#include <hip/hip_runtime.h>

// VectorQuantizer: for each of N rows of x (fp32, D=64), find argmin over
// K=8192 codebook rows of ||x - c||^2, computed in the reference's expanded
// form x_sq - 2*x.c + c_sq (fp32). Output int32 indices.
//
// Layout: lanes-over-codes. Each thread owns one code per 256-code tile
// (64 floats in VGPRs); each block owns ROWS=16 x-rows. Row data is
// wave-uniform -> scalar loads feeding v_fmac_f32 (1 VALU op per MAC).
// Running per-row best packed as (dist_bits<<32)|k in u64 so a u64 min gives
// numpy's first-occurrence tie-break (dist >= 0 so float bit order = order).

constexpr int N_ROWS  = 32768;
constexpr int K_CODES = 8192;
constexpr int D_DIM   = 64;
constexpr int TPB     = 256;
constexpr int ROWS    = 16;              // rows per block
constexpr int KTILES  = K_CODES / TPB;   // 32

__global__ void vq_argmin_kernel(const float* __restrict__ x,
                                 const float* __restrict__ cb,
                                 int* __restrict__ out) {
  const int tid = threadIdx.x;
  const int rowBase = blockIdx.x * ROWS;

  // Per-row ||x||^2 (wave-uniform), sequential fp32 fma like the main dot.
  float xsq[ROWS];
#pragma unroll
  for (int r = 0; r < ROWS; ++r) {
    const float* xr = x + (size_t)(rowBase + r) * D_DIM;
    float s = 0.f;
#pragma unroll
    for (int d = 0; d < D_DIM; ++d) s = fmaf(xr[d], xr[d], s);
    xsq[r] = s;
  }

  unsigned long long best[ROWS];
#pragma unroll
  for (int r = 0; r < ROWS; ++r) best[r] = ~0ull;

  // Opaque copy of the x base pointer; "touched" each tile iteration so LICM
  // cannot hoist all ROWS*D row loads out of the tile loop (register blowup).
  const float* xbase = x + (size_t)rowBase * D_DIM;

  for (int tile = 0; tile < KTILES; ++tile) {
    asm volatile("" : "+s"(xbase));   // defeat cross-tile load hoisting

    const int k = tile * TPB + tid;
    const float* cp = cb + (size_t)k * D_DIM;
    float creg[D_DIM];
#pragma unroll
    for (int d = 0; d < D_DIM; d += 4) {
      const float4 v = *(const float4*)(cp + d);
      creg[d]     = v.x;
      creg[d + 1] = v.y;
      creg[d + 2] = v.z;
      creg[d + 3] = v.w;
    }
    float csq = 0.f;
#pragma unroll
    for (int d = 0; d < D_DIM; ++d) csq = fmaf(creg[d], creg[d], csq);

#pragma unroll
    for (int r = 0; r < ROWS; ++r) {
      const float* xr = xbase + r * D_DIM;
      float dot = 0.f;
#pragma unroll
      for (int d = 0; d < D_DIM; ++d) dot = fmaf(creg[d], xr[d], dot);
      const float dist = fmaf(-2.f, dot, xsq[r]) + csq;
      const unsigned long long key =
          ((unsigned long long)__float_as_uint(dist) << 32) | (unsigned)k;
      if (key < best[r]) best[r] = key;
    }
  }

  // Block-wide u64-min reduction per row.
  __shared__ unsigned long long sb[ROWS * TPB];  // 32 KiB
#pragma unroll
  for (int r = 0; r < ROWS; ++r) sb[r * TPB + tid] = best[r];
  __syncthreads();

  for (int off = TPB / 2; off >= 1; off >>= 1) {
    if (tid < off) {
#pragma unroll
      for (int r = 0; r < ROWS; ++r) {
        const unsigned long long a = sb[r * TPB + tid];
        const unsigned long long b = sb[r * TPB + tid + off];
        if (b < a) sb[r * TPB + tid] = b;
      }
    }
    __syncthreads();
  }

  if (tid < ROWS) {
    out[rowBase + tid] = (int)(unsigned)(sb[tid * TPB] & 0xFFFFFFFFull);
  }
}

extern "C" void kernel_launch(void* const* d_in, const int* in_sizes, int n_in,
                              void* d_out, int out_size, void* d_ws, size_t ws_size,
                              hipStream_t stream) {
  const float* x  = (const float*)d_in[0];   // [N, 64] fp32
  const float* cb = (const float*)d_in[1];   // [K, 64] fp32
  int* out = (int*)d_out;                    // [N] int32

  vq_argmin_kernel<<<dim3(N_ROWS / ROWS), dim3(TPB), 0, stream>>>(x, cb, out);
}

// Round 2
// 545.843 us; speedup vs baseline: 4.4680x; 4.4680x over previous
//
#include <hip/hip_runtime.h>
#include <math.h>

// VectorQuantizer: argmin_k ||x_n - c_k||^2 for N=32768 rows, K=8192 codes,
// D=64, fp32. Expanded form (matches reference): xsq - 2*x.c + csq.
//
// Round-2 structure: row-ownership. Each thread holds RT=2 x-rows in VGPRs
// (128 regs, __launch_bounds__(256,2) to allow it); the codebook row is
// block-uniform -> SGPR via s_load, so the inner loop is v_fmac_f32 with one
// SGPR operand: 128 FMA + ~12 epilogue ops per code. Argmin is thread-local
// (strict < over ascending k = numpy first-occurrence tie-break). K is split
// KSPLIT ways across blocks for grid size; partial (dist,idx) per segment go
// to d_ws and a tiny reduce kernel combines (ascending segment order keeps
// the tie-break exact). csq[K] precomputed by a tiny kernel with the same
// sequential-fmaf chain as the round-1 kernel (absmax was 0 with it).

constexpr int NROWS = 32768;
constexpr int KC    = 8192;
constexpr int DD    = 64;
constexpr int TPB   = 256;
constexpr int RT    = 2;                       // rows per thread
constexpr int ROWBLKS = NROWS / (TPB * RT);    // 64

__global__ void csq_kernel(const float* __restrict__ cb, float* __restrict__ csq) {
  const int k = blockIdx.x * blockDim.x + threadIdx.x;
  const float* cp = cb + (size_t)k * DD;
  float s = 0.f;
#pragma unroll
  for (int d = 0; d < DD; ++d) s = fmaf(cp[d], cp[d], s);
  csq[k] = s;
}

__global__ __launch_bounds__(TPB, 2)
void vq_main_kernel(const float* __restrict__ x, const float* __restrict__ cb,
                    const float* __restrict__ csq,
                    float* __restrict__ segDist, int* __restrict__ segIdx,
                    int kseg) {
  const int tid  = threadIdx.x;
  const int seg  = blockIdx.y;
  const int row0 = (blockIdx.x * TPB + tid) * RT;

  // Load this thread's two x rows into registers (once).
  float x0[DD], x1[DD];
  const float* xp = x + (size_t)row0 * DD;
#pragma unroll
  for (int d = 0; d < DD; d += 4) {
    const float4 a = *(const float4*)(xp + d);
    x0[d] = a.x; x0[d + 1] = a.y; x0[d + 2] = a.z; x0[d + 3] = a.w;
  }
#pragma unroll
  for (int d = 0; d < DD; d += 4) {
    const float4 b = *(const float4*)(xp + DD + d);
    x1[d] = b.x; x1[d + 1] = b.y; x1[d + 2] = b.z; x1[d + 3] = b.w;
  }

  float xsq0 = 0.f, xsq1 = 0.f;
#pragma unroll
  for (int d = 0; d < DD; ++d) xsq0 = fmaf(x0[d], x0[d], xsq0);
#pragma unroll
  for (int d = 0; d < DD; ++d) xsq1 = fmaf(x1[d], x1[d], xsq1);

  const int kbase = seg * kseg;
  const float* cp = cb + (size_t)kbase * DD;   // block-uniform -> s_load
  const float* cq = csq + kbase;               // block-uniform -> s_load

  float b0 = INFINITY, b1 = INFINITY;
  int   i0 = kbase,    i1 = kbase;

  for (int j = 0; j < kseg; ++j) {
    float dot0 = 0.f, dot1 = 0.f;
#pragma unroll
    for (int d = 0; d < DD; ++d) {
      const float c = cp[d];                   // uniform scalar load
      dot0 = fmaf(c, x0[d], dot0);
      dot1 = fmaf(c, x1[d], dot1);
    }
    const float cs = cq[j];
    const float d0 = fmaf(-2.f, dot0, xsq0) + cs;
    const float d1 = fmaf(-2.f, dot1, xsq1) + cs;
    if (d0 < b0) { b0 = d0; i0 = kbase + j; }  // strict < : first k wins ties
    if (d1 < b1) { b1 = d1; i1 = kbase + j; }
    cp += DD;
  }

  const size_t o = (size_t)seg * NROWS + row0;
  segDist[o]     = b0;
  segDist[o + 1] = b1;
  segIdx[o]      = i0;
  segIdx[o + 1]  = i1;
}

__global__ void vq_reduce_kernel(const float* __restrict__ segDist,
                                 const int* __restrict__ segIdx,
                                 int* __restrict__ out, int ksplit) {
  const int n = blockIdx.x * blockDim.x + threadIdx.x;
  float b = INFINITY;
  int  bi = 0;
  for (int s = 0; s < ksplit; ++s) {           // ascending seg: ties -> lower k
    const float d = segDist[(size_t)s * NROWS + n];
    const int   i = segIdx [(size_t)s * NROWS + n];
    if (d < b) { b = d; bi = i; }
  }
  out[n] = bi;
}

extern "C" void kernel_launch(void* const* d_in, const int* in_sizes, int n_in,
                              void* d_out, int out_size, void* d_ws, size_t ws_size,
                              hipStream_t stream) {
  const float* x  = (const float*)d_in[0];   // [N, 64] fp32
  const float* cb = (const float*)d_in[1];   // [K, 64] fp32
  int* out = (int*)d_out;                    // [N] int32

  // Pick the largest KSPLIT (<=8) whose scratch fits in ws_size.
  int ksplit = 8;
  while (ksplit > 1 &&
         (size_t)4 * (KC + (size_t)2 * ksplit * NROWS) > ws_size) {
    ksplit >>= 1;
  }
  const int kseg = KC / ksplit;

  float* csq     = (float*)d_ws;                         // K floats
  float* segDist = csq + KC;                             // ksplit*N floats
  int*   segIdx  = (int*)(segDist + (size_t)ksplit * NROWS);

  csq_kernel<<<dim3(KC / TPB), dim3(TPB), 0, stream>>>(cb, csq);
  vq_main_kernel<<<dim3(ROWBLKS, ksplit), dim3(TPB), 0, stream>>>(
      x, cb, csq, segDist, segIdx, kseg);
  vq_reduce_kernel<<<dim3(NROWS / TPB), dim3(TPB), 0, stream>>>(
      segDist, segIdx, out, ksplit);
}

// Round 3
// 470.250 us; speedup vs baseline: 5.1863x; 1.1608x over previous
//
#include <hip/hip_runtime.h>
#include <math.h>

// VectorQuantizer: argmin_k ||x_n - c_k||^2, N=32768, K=8192, D=64, fp32.
// Expanded form (matches reference): xsq - 2*x.c + csq.
//
// Round-3: row-ownership with PINNED x registers. Round-2's counters showed
// VGPR_Count=48/76 — the compiler rematerialized the loop-invariant x loads
// inside the k-loop (vmcnt stalls, VALUBusy 52%). The asm "+v" pins below
// make each x value an asm result (not rematerializable), forcing all 128
// floats to stay live in VGPRs. __launch_bounds__(256,3) caps the allocator
// at 170 VGPRs (need ~150) => 3 waves/SIMD guaranteed.
// ksplit=12 => grid 768 = exactly 3 blocks/CU residency.
// Codebook row is block-uniform -> s_load into SGPRs; inner loop is
// v_fmac_f32 (1 SGPR operand), 128 FMA + ~10 epilogue ops per code.
// Tie-break: strict < over ascending k per segment, ascending segment in the
// reducer = numpy first-occurrence semantics. Same fmaf chains as the
// round-1/2 kernels that measured absmax 0.

constexpr int NROWS = 32768;
constexpr int KC    = 8192;
constexpr int DD    = 64;
constexpr int TPB   = 256;
constexpr int RT    = 2;                       // rows per thread
constexpr int ROWBLKS = NROWS / (TPB * RT);    // 64

__global__ void csq_kernel(const float* __restrict__ cb, float* __restrict__ csq) {
  const int k = blockIdx.x * blockDim.x + threadIdx.x;
  const float* cp = cb + (size_t)k * DD;
  float s = 0.f;
#pragma unroll
  for (int d = 0; d < DD; ++d) s = fmaf(cp[d], cp[d], s);
  csq[k] = s;
}

__global__ __launch_bounds__(TPB, 3)
void vq_main_kernel(const float* __restrict__ x, const float* __restrict__ cb,
                    const float* __restrict__ csq,
                    float* __restrict__ segDist, int* __restrict__ segIdx,
                    int ksplit) {
  const int tid  = threadIdx.x;
  const int seg  = blockIdx.y;
  const int row0 = (blockIdx.x * TPB + tid) * RT;

  // Segment bounds: integer split of [0,KC) into ksplit near-equal pieces.
  const int kbase = (int)(((long long)seg * KC) / ksplit);
  const int kend  = (int)(((long long)(seg + 1) * KC) / ksplit);

  // Load this thread's two x rows into registers (once).
  float x0[DD], x1[DD];
  const float* xp = x + (size_t)row0 * DD;
#pragma unroll
  for (int d = 0; d < DD; d += 4) {
    const float4 a = *(const float4*)(xp + d);
    x0[d] = a.x; x0[d + 1] = a.y; x0[d + 2] = a.z; x0[d + 3] = a.w;
  }
#pragma unroll
  for (int d = 0; d < DD; d += 4) {
    const float4 b = *(const float4*)(xp + DD + d);
    x1[d] = b.x; x1[d + 1] = b.y; x1[d + 2] = b.z; x1[d + 3] = b.w;
  }

  float xsq0 = 0.f, xsq1 = 0.f;
#pragma unroll
  for (int d = 0; d < DD; ++d) xsq0 = fmaf(x0[d], x0[d], xsq0);
#pragma unroll
  for (int d = 0; d < DD; ++d) xsq1 = fmaf(x1[d], x1[d], xsq1);

  // Pin every x value into a VGPR: asm results cannot be rematerialized,
  // so the allocator must keep them live across the k-loop.
#pragma unroll
  for (int d = 0; d < DD; ++d) {
    asm volatile("" : "+v"(x0[d]));
    asm volatile("" : "+v"(x1[d]));
  }

  const float* cp = cb + (size_t)kbase * DD;   // block-uniform -> s_load

  float b0 = INFINITY, b1 = INFINITY;
  int   i0 = kbase,    i1 = kbase;

  for (int j = kbase; j < kend; ++j) {
    float dot0 = 0.f, dot1 = 0.f;
#pragma unroll
    for (int d = 0; d < DD; ++d) {
      const float c = cp[d];                   // uniform scalar load
      dot0 = fmaf(c, x0[d], dot0);
      dot1 = fmaf(c, x1[d], dot1);
    }
    const float cs = csq[j];                   // uniform scalar load
    const float d0 = fmaf(-2.f, dot0, xsq0) + cs;
    const float d1 = fmaf(-2.f, dot1, xsq1) + cs;
    if (d0 < b0) { b0 = d0; i0 = j; }          // strict < : first k wins ties
    if (d1 < b1) { b1 = d1; i1 = j; }
    cp += DD;
  }

  const size_t o = (size_t)seg * NROWS + row0;
  segDist[o]     = b0;
  segDist[o + 1] = b1;
  segIdx[o]      = i0;
  segIdx[o + 1]  = i1;
}

__global__ void vq_reduce_kernel(const float* __restrict__ segDist,
                                 const int* __restrict__ segIdx,
                                 int* __restrict__ out, int ksplit) {
  const int n = blockIdx.x * blockDim.x + threadIdx.x;
  float b = INFINITY;
  int  bi = 0;
  for (int s = 0; s < ksplit; ++s) {           // ascending seg: ties -> lower k
    const float d = segDist[(size_t)s * NROWS + n];
    const int   i = segIdx [(size_t)s * NROWS + n];
    if (d < b) { b = d; bi = i; }
  }
  out[n] = bi;
}

extern "C" void kernel_launch(void* const* d_in, const int* in_sizes, int n_in,
                              void* d_out, int out_size, void* d_ws, size_t ws_size,
                              hipStream_t stream) {
  const float* x  = (const float*)d_in[0];   // [N, 64] fp32
  const float* cb = (const float*)d_in[1];   // [K, 64] fp32
  int* out = (int*)d_out;                    // [N] int32

  // Largest ksplit (by preference) whose scratch fits in ws_size.
  // 12 => grid 768 = exactly 3 blocks/CU at 3 waves/SIMD.
  const int candidates[5] = {12, 8, 4, 2, 1};
  int ksplit = 1;
  for (int c = 0; c < 5; ++c) {
    const size_t need = (size_t)4 * KC + (size_t)8 * candidates[c] * NROWS;
    if (need <= ws_size) { ksplit = candidates[c]; break; }
  }

  float* csq     = (float*)d_ws;                         // K floats
  float* segDist = csq + KC;                             // ksplit*N floats
  int*   segIdx  = (int*)(segDist + (size_t)ksplit * NROWS);

  csq_kernel<<<dim3(KC / TPB), dim3(TPB), 0, stream>>>(cb, csq);
  vq_main_kernel<<<dim3(ROWBLKS, ksplit), dim3(TPB), 0, stream>>>(
      x, cb, csq, segDist, segIdx, ksplit);
  vq_reduce_kernel<<<dim3(NROWS / TPB), dim3(TPB), 0, stream>>>(
      segDist, segIdx, out, ksplit);
}